// Round 16
// baseline (155.024 us; speedup 1.0000x reference)
//
#include <hip/hip_runtime.h>
#include <math.h>

namespace {

constexpr int cB = 32, cL = 128, cG = 64, cD = 256;
constexpr int cHD = 128, cH = 256;
constexpr int cN = 8, cK = 4;
constexpr int cNI = 128, cRH = 512;
constexpr int cE = 2048;
constexpr float cEPS = 1e-5f;

typedef __bf16 bf16x8 __attribute__((ext_vector_type(8)));
typedef float f32x4 __attribute__((ext_vector_type(4)));

__device__ __forceinline__ f32x4 mfma16(bf16x8 a, bf16x8 b, f32x4 c) {
    return __builtin_amdgcn_mfma_f32_16x16x32_bf16(a, b, c, 0, 0, 0);
}

__device__ __forceinline__ float bf2f(unsigned short u) {
    unsigned int x = ((unsigned int)u) << 16;
    return __uint_as_float(x);
}
__device__ __forceinline__ unsigned short f2bf(float f) {
    unsigned int x = __float_as_uint(f);
    unsigned int r = (x + 0x7fffu + ((x >> 16) & 1u)) >> 16;  // RNE
    return (unsigned short)r;
}
__device__ __forceinline__ float frcp(float x) { return __builtin_amdgcn_rcpf(x); }
__device__ __forceinline__ float fsig(float x) { return frcp(1.f + __expf(-x)); }
__device__ __forceinline__ float ftanh(float x) { return 1.f - 2.f * frcp(__expf(2.f * x) + 1.f); }
__device__ __forceinline__ float nls(float x) {
    return (x >= 0.f) ? log1pf(expf(-x)) : (log1pf(expf(x)) - x);
}
__device__ __forceinline__ bf16x8 cvt8(const float* __restrict__ p) {
    float4 a = *(const float4*)p, b = *(const float4*)(p + 4);
    bf16x8 v;
    v[0] = (__bf16)a.x; v[1] = (__bf16)a.y; v[2] = (__bf16)a.z; v[3] = (__bf16)a.w;
    v[4] = (__bf16)b.x; v[5] = (__bf16)b.y; v[6] = (__bf16)b.z; v[7] = (__bf16)b.w;
    return v;
}

// lgkm-only barrier: LDS ping-pong needs lgkmcnt ordering, NOT a vmcnt(0) drain.
__device__ __forceinline__ void bar_lgkm() {
    asm volatile("s_waitcnt lgkmcnt(0)\n\ts_barrier" ::: "memory");
}

// ---------------------------------------------------------------------------
// 1) token embedding + scatter_sum (verified).
__global__ __launch_bounds__(256) void k_embed(
    const int* __restrict__ seq, const int* __restrict__ p2g,
    const float* __restrict__ emb, float* __restrict__ x_seq) {
    __shared__ float xl[cG * cD];
    __shared__ int toks[cL], grps[cL];
    int b = blockIdx.x, t = threadIdx.x;
    if (t < 128) toks[t] = seq[b * cL + t];
    else grps[t - 128] = p2g[b * cL + (t - 128)];
    for (int g = 0; g < cG; ++g) xl[g * cD + t] = 0.f;
    __syncthreads();
    for (int l = 0; l < cL; l += 4) {
        float v0 = emb[(size_t)toks[l + 0] * cD + t];
        float v1 = emb[(size_t)toks[l + 1] * cD + t];
        float v2 = emb[(size_t)toks[l + 2] * cD + t];
        float v3 = emb[(size_t)toks[l + 3] * cD + t];
        xl[grps[l + 0] * cD + t] += v0;
        xl[grps[l + 1] * cD + t] += v1;
        xl[grps[l + 2] * cD + t] += v2;
        xl[grps[l + 3] * cD + t] += v3;
    }
    for (int g = 0; g < cG; ++g)
        x_seq[(g * cB + b) * cD + t] = xl[g * cD + t];
}

// ---------------------------------------------------------------------------
// 2) LSTM input GEMM via MFMA (verified).
__global__ __launch_bounds__(512) void k_gemm_in(
    const float* __restrict__ x_seq,
    const float* __restrict__ wih_f, const float* __restrict__ wih_b,
    const float* __restrict__ bih_f, const float* __restrict__ bhh_f,
    const float* __restrict__ bih_b, const float* __restrict__ bhh_b,
    float* __restrict__ pre) {
    int ns = blockIdx.x, g = blockIdx.y;
    int t = threadIdx.x;
    int w = t >> 6, l = t & 63, lc = l & 15, lk = l >> 4;
    int gn = ns * 128 + w * 16 + lc;
    const float* wrow = (gn < 512) ? (wih_f + (size_t)gn * cD)
                                   : (wih_b + (size_t)(gn - 512) * cD);
    const float* xb0 = x_seq + ((size_t)g * 32 + lc) * cD;
    const float* xb1 = x_seq + ((size_t)g * 32 + 16 + lc) * cD;
    f32x4 acc0 = {0.f, 0.f, 0.f, 0.f}, acc1 = {0.f, 0.f, 0.f, 0.f};
#pragma unroll
    for (int kf = 0; kf < 8; ++kf) {
        int ko = kf * 32 + lk * 8;
        bf16x8 a = cvt8(wrow + ko);
        bf16x8 b0 = cvt8(xb0 + ko);
        bf16x8 b1 = cvt8(xb1 + ko);
        acc0 = mfma16(a, b0, acc0);
        acc1 = mfma16(a, b1, acc1);
    }
    int nb = ns * 128 + w * 16 + lk * 4;
    float4 bv;
    if (nb < 512) {
        float4 u = *(const float4*)(bih_f + nb);
        float4 v = *(const float4*)(bhh_f + nb);
        bv = make_float4(u.x + v.x, u.y + v.y, u.z + v.z, u.w + v.w);
    } else {
        float4 u = *(const float4*)(bih_b + nb - 512);
        float4 v = *(const float4*)(bhh_b + nb - 512);
        bv = make_float4(u.x + v.x, u.y + v.y, u.z + v.z, u.w + v.w);
    }
    size_t base = ((size_t)g * 256 + (nb >> 2)) * 32;
    *(float4*)(pre + (base + lc) * 4) =
        make_float4(acc0[0] + bv.x, acc0[1] + bv.y, acc0[2] + bv.z, acc0[3] + bv.w);
    *(float4*)(pre + (base + 16 + lc) * 4) =
        make_float4(acc1[0] + bv.x, acc1[1] + bv.y, acc1[2] + bv.z, acc1[3] + bv.w);
}

// ---------------------------------------------------------------------------
// 3) MFMA LSTM — round-8 proven config (59.6us, VGPR 76, no spill).
__device__ __forceinline__ void lstm_step(
    f32x4 (&acc)[4], float (&cst)[4], const bf16x8 (&wf)[4][4],
    const unsigned short* __restrict__ hr, unsigned short* __restrict__ hw,
    const int (&rdo)[4], int wro,
    const float* __restrict__ preb, int gpre, bool dopre,
    unsigned short* __restrict__ hob, int g) {
    bf16x8 hf[4];
#pragma unroll
    for (int kf = 0; kf < 4; ++kf)
        hf[kf] = *(const bf16x8*)((const char*)hr + rdo[kf]);
#pragma unroll
    for (int kf = 0; kf < 4; ++kf)
#pragma unroll
        for (int q = 0; q < 4; ++q)
            acc[q] = mfma16(wf[q][kf], hf[kf], acc[q]);
    float hv[4];
#pragma unroll
    for (int r = 0; r < 4; ++r) {
        float ig = fsig(acc[0][r]);
        float fg = fsig(acc[1][r]);
        float gg = ftanh(acc[2][r]);
        float og = fsig(acc[3][r]);
        float cv = fg * cst[r] + ig * gg;
        cst[r] = cv;
        hv[r] = og * ftanh(cv);
    }
    if (dopre) {
#pragma unroll
        for (int q = 0; q < 4; ++q)
            acc[q] = *(const f32x4*)(preb + (size_t)gpre * 32768 + q * 4096);
    }
    unsigned int p0 = (unsigned int)f2bf(hv[0]) | ((unsigned int)f2bf(hv[1]) << 16);
    unsigned int p1 = (unsigned int)f2bf(hv[2]) | ((unsigned int)f2bf(hv[3]) << 16);
    *(uint2*)((char*)hw + wro) = make_uint2(p0, p1);
    *(uint2*)(hob + (size_t)g * 8192) = make_uint2(p0, p1);
    bar_lgkm();
}

__global__ __launch_bounds__(512, 2) void k_lstm_m(
    const float* __restrict__ pre,
    const float* __restrict__ whh_f, const float* __restrict__ whh_b,
    unsigned short* __restrict__ h_out) {
    __shared__ __align__(16) unsigned short hl[2][2048];
    int t = threadIdx.x;
    int w = t >> 6, l = t & 63, lc = l & 15, lk = l >> 4;
    int dir = blockIdx.x >> 1, bg = (blockIdx.x & 1) * 16;
    const float* whh = dir ? whh_b : whh_f;
    bf16x8 wf[4][4];
#pragma unroll
    for (int q = 0; q < 4; ++q) {
        int n = q * 128 + w * 16 + lc;
#pragma unroll
        for (int kf = 0; kf < 4; ++kf)
            wf[q][kf] = cvt8(whh + (size_t)n * 128 + kf * 32 + lk * 8);
    }
    *(uint2*)&hl[1][t * 4] = make_uint2(0u, 0u);
    const float* preb = pre + ((size_t)(dir * 128 + w * 4 + lk) * 32 + (bg + lc)) * 4;
    unsigned short* hob = h_out + ((size_t)(dir * 32 + bg + lc) * 128 + w * 16 + lk * 4);
    int rdo[4];
#pragma unroll
    for (int kf = 0; kf < 4; ++kf)
        rdo[kf] = (lc * 256 + kf * 64 + lk * 16) ^ (lc << 4);
    int wro = (lc * 256 + w * 32 + lk * 8) ^ (lc << 4);
    f32x4 accA[4], accB[4];
    float cst[4] = {0.f, 0.f, 0.f, 0.f};
    int g0 = dir ? 63 : 0;
    int sgn = dir ? -1 : 1;
#pragma unroll
    for (int q = 0; q < 4; ++q) accA[q] = *(const f32x4*)(preb + (size_t)g0 * 32768 + q * 4096);
#pragma unroll
    for (int q = 0; q < 4; ++q) accB[q] = *(const f32x4*)(preb + (size_t)(g0 + sgn) * 32768 + q * 4096);
    bar_lgkm();
    for (int s = 0; s < 64; s += 2) {
        int ga = g0 + sgn * s;
        lstm_step(accA, cst, wf, hl[1], hl[0], rdo, wro, preb, ga + 2 * sgn, s < 62, hob, ga);
        lstm_step(accB, cst, wf, hl[0], hl[1], rdo, wro, preb, ga + 3 * sgn, s < 61, hob, ga + sgn);
    }
}

// ---------------------------------------------------------------------------
// 4) gather(+sum over K) -> transposed hsumT[c][n] (verified).
__global__ __launch_bounds__(256) void k_gather(
    const int* __restrict__ idx, const int* __restrict__ p2g,
    const unsigned short* __restrict__ h_out, float* __restrict__ hsumT) {
    int bn = blockIdx.x;
    int b = bn >> 3;
    int t = threadIdx.x;
    int dirq = t >> 7, hh = t & 127;
    int l0 = idx[bn * cK + 0], l1 = idx[bn * cK + 1];
    int l2 = idx[bn * cK + 2], l3 = idx[bn * cK + 3];
    int g0 = p2g[b * cL + l0], g1 = p2g[b * cL + l1];
    int g2 = p2g[b * cL + l2], g3 = p2g[b * cL + l3];
    size_t ro = (size_t)(dirq * 32 + b) * 128 + hh;
    float a = bf2f(h_out[(size_t)g0 * 8192 + ro]) + bf2f(h_out[(size_t)g1 * 8192 + ro]) +
              bf2f(h_out[(size_t)g2 * 8192 + ro]) + bf2f(h_out[(size_t)g3 * 8192 + ro]);
    hsumT[(size_t)t * 256 + bn] = a;
}

// ---------------------------------------------------------------------------
// 5) fused projection + BatchNorm; dst side also emits bf16 copy (verified).
__global__ __launch_bounds__(256) void k_proj_bn(
    const float* __restrict__ hsumT,
    const float* __restrict__ w_src, const float* __restrict__ b_src,
    const float* __restrict__ w_dst, const float* __restrict__ b_dst,
    const float* __restrict__ g_src, const float* __restrict__ bb_src,
    const float* __restrict__ g_dst, const float* __restrict__ bb_dst,
    float* __restrict__ hd_bn, float* __restrict__ tl_bn,
    unsigned short* __restrict__ tl_bf) {
    int which = blockIdx.x, c = blockIdx.y, t = threadIdx.x;
    __shared__ float ws[256];
    __shared__ float ssum[256], ssq[256];
    ws[t] = (which ? w_dst : w_src)[(size_t)c * cH + t];
    __syncthreads();
    float acc = (which ? b_dst : b_src)[c];
#pragma unroll 8
    for (int k = 0; k < cH; ++k)
        acc += ws[k] * hsumT[(size_t)k * 256 + t];
    ssum[t] = acc;
    ssq[t] = acc * acc;
    __syncthreads();
    for (int o = 128; o > 0; o >>= 1) {
        if (t < o) { ssum[t] += ssum[t + o]; ssq[t] += ssq[t + o]; }
        __syncthreads();
    }
    float mean = ssum[0] * (1.f / 256.f);
    float var = ssq[0] * (1.f / 256.f) - mean * mean;
    float gam = which ? g_dst[c] : g_src[c];
    float bet = which ? bb_dst[c] : bb_src[c];
    float scale = gam * rsqrtf(var + cEPS);
    float val = (acc - mean) * scale + bet;
    (which ? tl_bn : hd_bn)[(size_t)t * cNI + c] = val;
    if (which) tl_bf[(size_t)t * cNI + c] = f2bf(val);
}

// ---------------------------------------------------------------------------
// 6) FUSED NTL (+BN2+tanh+u): per-rh block computes lin, T = hd@W, T->LDS,
//    P = T.tl^T diagonal tiles, in-block BN stats + scale/shift broadcast,
//    act[rh][e] = u[rh]*tanh(BN(P)) stored bf16. No pre2 / part2 buffers.
__global__ __launch_bounds__(256, 2) void k_ntl(
    const float* __restrict__ hd_bn, const float* __restrict__ tl_bn,
    const unsigned short* __restrict__ tl_bf,
    const float* __restrict__ ntl_w, const float* __restrict__ ntl_v,
    const float* __restrict__ ntl_b, const float* __restrict__ ntl_u,
    const float* __restrict__ g2, const float* __restrict__ b2,
    unsigned short* __restrict__ act) {
    __shared__ __align__(16) unsigned short Tl[256 * 128];  // 64KB; first 32KB = W stage
    __shared__ float vsh[256];
    __shared__ float lsl[256], ldl[256];
    __shared__ float rs[8];
    int rh = blockIdx.x, t = threadIdx.x;
    int w = t >> 6, l = t & 63, lc = l & 15, lk = l >> 4;
    vsh[t] = ntl_v[(size_t)rh * 256 + t];
    unsigned short* wl = Tl;
    {
        const float* wbase = ntl_w + (size_t)rh * 16384;
        int k = t >> 1, c0 = (t & 1) * 64;
        int sw = ((k >> 3) & 3) << 4;
#pragma unroll
        for (int u = 0; u < 8; ++u) {
            bf16x8 v = cvt8(wbase + k * 128 + c0 + u * 8);
            *(bf16x8*)((char*)wl + ((k * 256 + (c0 + u * 8) * 2) ^ sw)) = v;
        }
    }
    __syncthreads();
    // lin part -> LDS only
    {
        const float* hr = hd_bn + (size_t)t * cNI;
        const float* tr = tl_bn + (size_t)t * cNI;
        float a1 = 0.f, a2 = 0.f;
#pragma unroll 8
        for (int i = 0; i < cNI; i += 4) {
            float4 h4 = *(const float4*)(hr + i);
            float4 t4 = *(const float4*)(tr + i);
            a1 += h4.x * vsh[i] + h4.y * vsh[i + 1] + h4.z * vsh[i + 2] + h4.w * vsh[i + 3];
            a2 += t4.x * vsh[128 + i] + t4.y * vsh[128 + i + 1] + t4.z * vsh[128 + i + 2] + t4.w * vsh[128 + i + 3];
        }
        lsl[t] = a1;
        ldl[t] = a2;
    }
    // phase 1: T = hd @ W
    f32x4 acc[4][8] = {};
#pragma unroll
    for (int kf = 0; kf < 4; ++kf) {
        bf16x8 af[4];
#pragma unroll
        for (int mt = 0; mt < 4; ++mt) {
            int m = w * 64 + mt * 16 + lc;
            af[mt] = cvt8(hd_bn + (size_t)m * 128 + kf * 32 + lk * 8);
        }
#pragma unroll
        for (int nt = 0; nt < 8; ++nt) {
            int kb = (kf * 32 + lk * 8) * 256;
            int jb = (nt * 16 + lc) * 2;
            bf16x8 bv = *(const bf16x8*)((char*)wl + ((kb + jb) ^ (lk << 4)));
#pragma unroll
            for (int mt = 0; mt < 4; ++mt) acc[mt][nt] = mfma16(af[mt], bv, acc[mt][nt]);
        }
    }
    __syncthreads();  // all W reads done; safe to overwrite with T
#pragma unroll
    for (int mt = 0; mt < 4; ++mt) {
#pragma unroll
        for (int nt = 0; nt < 8; ++nt) {
#pragma unroll
            for (int r = 0; r < 4; ++r) {
                int row = w * 64 + mt * 16 + lk * 4 + r;
                int col = nt * 16 + lc;
                int byte = (row * 256 + col * 2) ^ ((row & 7) << 4);
                *(unsigned short*)((char*)Tl + byte) = f2bf(acc[mt][nt][r]);
            }
        }
    }
    __syncthreads();
    // phase 2: diagonal 16x16 tiles; keep-condition is lane-uniform:
    // (i>>3)==jg  <=>  (lk>=2)==(lc>=8)
    float nb = ntl_b[rh];
    float sm = 0.f, sq = 0.f;
    float vals[4][4];
    int jg = lc >> 3;
#pragma unroll
    for (int p = 0; p < 4; ++p) {
        int ti = w * 4 + p;
        int arow = ti * 16 + lc;
        f32x4 d = {0.f, 0.f, 0.f, 0.f};
#pragma unroll
        for (int kf = 0; kf < 4; ++kf) {
            const char* ta = (const char*)Tl +
                ((arow * 256 + (kf * 32 + lk * 8) * 2) ^ ((arow & 7) << 4));
            bf16x8 a = *(const bf16x8*)ta;
            bf16x8 b = *(const bf16x8*)(tl_bf + (size_t)arow * 128 + kf * 32 + lk * 8);
            d = mfma16(a, b, d);
        }
#pragma unroll
        for (int r = 0; r < 4; ++r) {
            int i = lk * 4 + r;
            float v = d[r] + lsl[ti * 16 + i] + ldl[arow] + nb;
            vals[p][r] = v;
            if ((i >> 3) == jg) { sm += v; sq += v * v; }
        }
    }
#pragma unroll
    for (int o = 32; o > 0; o >>= 1) {
        sm += __shfl_down(sm, o);
        sq += __shfl_down(sq, o);
    }
    if (l == 0) { rs[w] = sm; rs[4 + w] = sq; }
    __syncthreads();
    float S = rs[0] + rs[1] + rs[2] + rs[3];
    float Q = rs[4] + rs[5] + rs[6] + rs[7];
    float mean = S * (1.f / 2048.f);
    float var = Q * (1.f / 2048.f) - mean * mean;
    float scv = g2[rh] * rsqrtf(var + cEPS);
    float shv = b2[rh] - mean * scv;
    float uu = ntl_u[rh];
    unsigned short* arow_base = act + (size_t)rh * cE;
#pragma unroll
    for (int p = 0; p < 4; ++p) {
        int ti = w * 4 + p;
#pragma unroll
        for (int r = 0; r < 4; ++r) {
            int i = lk * 4 + r;
            if ((i >> 3) == jg) {
                int e = (ti * 2 + jg) * 64 + (i & 7) * 8 + (lc & 7);
                arow_base[e] = f2bf(uu * ftanh(fmaf(vals[p][r], scv, shv)));
            }
        }
    }
}

// ---------------------------------------------------------------------------
// 7) logit = sum of 32 bf16 act terms + fused loss partials (pure bandwidth).
__global__ __launch_bounds__(256) void k_final(
    const unsigned short* __restrict__ act, const int* __restrict__ mask,
    float* __restrict__ out, float* __restrict__ part) {
    int r = blockIdx.y, et = blockIdx.x;
    int t = threadIdx.x;
    int e = et * 256 + t;
    float a = 0.f;
#pragma unroll
    for (int h = 0; h < 32; ++h)
        a += bf2f(act[(size_t)(r * 32 + h) * cE + e]);
    out[(size_t)e * 16 + r] = a;
    int m = mask[(size_t)e * 16 + r];
    bool mb = (m != 0);
    bool eq = ((a > 0.f) == mb);
    float nll = mb ? nls(a) : -logf(1.f / (1.f + expf(a)) + 1e-5f);
    float corr = eq ? 1.f : 0.f;
    unsigned long long bal = __ballot(eq);
    float em = (bal == ~0ull) ? 1.f : 0.f;
#pragma unroll
    for (int o = 32; o > 0; o >>= 1) {
        nll += __shfl_down(nll, o);
        corr += __shfl_down(corr, o);
    }
    if ((t & 63) == 0) {
        int bg = et * 4 + (t >> 6);
        float* p = part + ((size_t)bg * 16 + r) * 4;
        p[0] = nll; p[1] = corr; p[2] = em;
    }
}

// ---------------------------------------------------------------------------
// 8) final loss reduction
__global__ void k_loss_fin(const float* __restrict__ part, float* __restrict__ out) {
    int t = threadIdx.x;
    float nll = 0.f, corr = 0.f, em = 0.f;
    if (t < 32) {
        em = 1.f;
        for (int r = 0; r < 16; ++r) {
            const float* p = part + ((size_t)t * 16 + r) * 4;
            nll += p[0]; corr += p[1]; em = fminf(em, p[2]);
        }
    }
#pragma unroll
    for (int o = 32; o > 0; o >>= 1) {
        nll += __shfl_down(nll, o);
        corr += __shfl_down(corr, o);
        em += __shfl_down(em, o);
    }
    if (t == 0) {
        out[32768] = nll / 32.f;
        out[32769] = corr / 32768.f;
        out[32770] = em / 32.f;
    }
}

}  // namespace

extern "C" void kernel_launch(void* const* d_in, const int* in_sizes, int n_in,
                              void* d_out, int out_size, void* d_ws, size_t ws_size,
                              hipStream_t stream) {
    (void)in_sizes; (void)n_in; (void)out_size; (void)ws_size;
    const int* seq = (const int*)d_in[0];
    const int* p2g = (const int*)d_in[1];
    const int* idx = (const int*)d_in[2];
    const int* mask = (const int*)d_in[5];
    const float* emb = (const float*)d_in[6];
    const float* wih_f = (const float*)d_in[7];
    const float* whh_f = (const float*)d_in[8];
    const float* bih_f = (const float*)d_in[9];
    const float* bhh_f = (const float*)d_in[10];
    const float* wih_b = (const float*)d_in[11];
    const float* whh_b = (const float*)d_in[12];
    const float* bih_b = (const float*)d_in[13];
    const float* bhh_b = (const float*)d_in[14];
    const float* lsw = (const float*)d_in[15];
    const float* lsb = (const float*)d_in[16];
    const float* ldw = (const float*)d_in[17];
    const float* ldb = (const float*)d_in[18];
    const float* bn_sg = (const float*)d_in[19];
    const float* bn_sb = (const float*)d_in[20];
    const float* bn_dg = (const float*)d_in[21];
    const float* bn_db = (const float*)d_in[22];
    const float* ntlw = (const float*)d_in[23];
    const float* ntlv = (const float*)d_in[24];
    const float* ntlb = (const float*)d_in[25];
    const float* ntlu = (const float*)d_in[26];
    const float* bn2g = (const float*)d_in[27];
    const float* bn2b = (const float*)d_in[28];
    float* out = (float*)d_out;
    char* ws = (char*)d_ws;

    float* x_seq = (float*)(ws + 0);
    float* pre = (float*)(ws + 2097152);
    size_t off = 33554432;
    unsigned short* h_out = (unsigned short*)(ws + off); off += 1048576;
    float* hsumT = (float*)(ws + off); off += 262144;
    float* hd_bn = (float*)(ws + off); off += 131072;
    float* tl_bn = (float*)(ws + off); off += 131072;
    unsigned short* tl_bf = (unsigned short*)(ws + off); off += 65536;
    unsigned short* act = (unsigned short*)(ws + off); off += 2097152;
    float* part = (float*)(ws + off); off += 8192;

    k_embed<<<32, 256, 0, stream>>>(seq, p2g, emb, x_seq);
    k_gemm_in<<<dim3(8, 64), 512, 0, stream>>>(x_seq, wih_f, wih_b, bih_f, bhh_f, bih_b, bhh_b, pre);
    k_lstm_m<<<4, 512, 0, stream>>>(pre, whh_f, whh_b, h_out);
    k_gather<<<256, 256, 0, stream>>>(idx, p2g, h_out, hsumT);
    k_proj_bn<<<dim3(2, 128), 256, 0, stream>>>(hsumT, lsw, lsb, ldw, ldb,
                                                bn_sg, bn_sb, bn_dg, bn_db, hd_bn, tl_bn, tl_bf);
    k_ntl<<<512, 256, 0, stream>>>(hd_bn, tl_bn, tl_bf, ntlw, ntlv, ntlb, ntlu, bn2g, bn2b, act);
    k_final<<<dim3(8, 16), 256, 0, stream>>>(act, mask, out, part);
    k_loss_fin<<<1, 64, 0, stream>>>(part, out);
}